// Round 1
// baseline (561.748 us; speedup 1.0000x reference)
//
#include <hip/hip_runtime.h>
#include <hip/hip_bf16.h>

#define H 512
#define W 512
#define C 32
#define O 32
#define TW 64
#define TH 8

using bf16x8 = __attribute__((ext_vector_type(8))) short;
using f32x4  = __attribute__((ext_vector_type(4))) float;

__device__ __forceinline__ unsigned short f2bf(float f) {
    union { float f; unsigned u; } c; c.f = f;
    unsigned r = c.u + 0x7fffu + ((c.u >> 16) & 1u);
    return (unsigned short)(r >> 16);
}

// Reconstruct w[o, ci, 3, 3] from CP factors, store bf16 as w[s][o][ci]
// (ci contiguous => B-fragment loads are single 16B reads).
// o = i*16 + j*4 + k (in-dims of k0/k1/k2), ci = a*16 + b*4 + c (out-dims),
// matching the reference's 'gijkabchw' -> (32, 32, 3, 3) reshape.
__global__ void recon_w(const float* __restrict__ k0, const float* __restrict__ k1,
                        const float* __restrict__ k2, const float* __restrict__ k3,
                        unsigned short* __restrict__ wout) {
    int idx = blockIdx.x * 256 + threadIdx.x;
    if (idx >= 9 * 32 * 32) return;
    int ci = idx & 31;
    int o  = (idx >> 5) & 31;
    int s  = idx >> 10;                 // 0..8 = dh*3+dw
    int i = o >> 4, j = (o >> 2) & 3, k = o & 3;
    int a = ci >> 4, b = (ci >> 2) & 3, c = ci & 3;
    float acc = 0.f;
    #pragma unroll
    for (int r = 0; r < 8; ++r)
        acc += k0[(i*2 + a)*8 + r] * k1[(j*4 + b)*8 + r]
             * k2[(k*4 + c)*8 + r] * k3[s*8 + r];
    wout[idx] = f2bf(acc);
}

// Implicit-GEMM conv: per block, a TW x TH pixel tile for all 32 out chans.
// MFMA 16x16x32 bf16: M=16 pixels (x-consecutive), N=16 o, K=32 ci; 9 taps.
__launch_bounds__(256, 2)
__global__ void conv_mfma(const float* __restrict__ x,
                          const unsigned short* __restrict__ wq,
                          const float* __restrict__ bias,
                          float* __restrict__ out) {
    // [row][gx][ci], ci contiguous => A-frag = one ds_read_b128
    __shared__ __align__(16) unsigned short sx[TH + 2][TW + 2][C];

    const int tid = threadIdx.x;
    const int bid = blockIdx.x;
    const int n  = bid >> 9;            // 512 tiles per image
    const int r2 = bid & 511;
    const int ty = r2 >> 3;             // 0..63
    const int tx = r2 & 7;              // 0..7
    const int y0 = ty * TH, x0 = tx * TW;

    const int lane = tid & 63;
    const int pix  = lane & 15;
    const int quad = lane >> 4;

    // B fragments in registers: B[k=ci=quad*8+j][n=o=h*16+pix]
    bf16x8 bw[9][2];
    #pragma unroll
    for (int s = 0; s < 9; ++s)
        #pragma unroll
        for (int h = 0; h < 2; ++h)
            bw[s][h] = *(const bf16x8*)(wq + ((s*32 + h*16 + pix)*32 + quad*8));

    // Stage x tile -> LDS bf16. Task = (row, ciq, gx); consecutive tid =>
    // consecutive gx with fixed (ci,row) => coalesced global dword loads.
    // Each task gathers 8 ci values for one pixel, packs one 16B LDS write.
    for (int task = tid; task < (TH + 2) * 4 * (TW + 2); task += 256) {
        int gxl = task % (TW + 2);
        int t2  = task / (TW + 2);
        int ciq = t2 & 3;
        int row = t2 >> 2;
        int gy = y0 + row - 1;
        int gx = x0 + gxl - 1;
        bool inb = (gy >= 0) && (gy < H) && (gx >= 0) && (gx < W);
        const float* p = x + (((n*C + ciq*8)*H + gy)*W + gx);
        float v[8];
        #pragma unroll
        for (int j2 = 0; j2 < 8; ++j2) v[j2] = inb ? p[j2 * H * W] : 0.f;
        uint4 pk;
        pk.x = (unsigned)f2bf(v[0]) | ((unsigned)f2bf(v[1]) << 16);
        pk.y = (unsigned)f2bf(v[2]) | ((unsigned)f2bf(v[3]) << 16);
        pk.z = (unsigned)f2bf(v[4]) | ((unsigned)f2bf(v[5]) << 16);
        pk.w = (unsigned)f2bf(v[6]) | ((unsigned)f2bf(v[7]) << 16);
        *(uint4*)&sx[row][gxl][ciq * 8] = pk;
    }
    __syncthreads();

    const int wave = tid >> 6;          // each wave: 2 rows x 64 px
    const float b0 = bias[pix];
    const float b1 = bias[16 + pix];

    for (int mt = 0; mt < 8; ++mt) {
        const int rr = mt >> 2;
        const int xm = (mt & 3) << 4;
        const int wrow = wave * 2 + rr;
        f32x4 acc0 = {0.f, 0.f, 0.f, 0.f};
        f32x4 acc1 = {0.f, 0.f, 0.f, 0.f};
        #pragma unroll
        for (int s = 0; s < 9; ++s) {
            const int dy = s / 3, dx = s % 3;  // const-folded (unrolled)
            // A[m=pix][k=ci]: x at (y0+wrow+dy-1, x0+xm+pix+dx-1)
            bf16x8 a = *(const bf16x8*)&sx[wrow + dy][xm + pix + dx][quad * 8];
            acc0 = __builtin_amdgcn_mfma_f32_16x16x32_bf16(a, bw[s][0], acc0, 0, 0, 0);
            acc1 = __builtin_amdgcn_mfma_f32_16x16x32_bf16(a, bw[s][1], acc1, 0, 0, 0);
        }
        // D: m = quad*4 + reg (pixel), n = pix (o)
        const int gy = y0 + wrow;
        const int base0 = ((n*O + pix)      * H + gy) * W + x0 + xm + quad * 4;
        const int base1 = ((n*O + 16 + pix) * H + gy) * W + x0 + xm + quad * 4;
        #pragma unroll
        for (int t = 0; t < 4; ++t) {
            out[base0 + t] = acc0[t] + b0;
            out[base1 + t] = acc1[t] + b1;
        }
    }
}

extern "C" void kernel_launch(void* const* d_in, const int* in_sizes, int n_in,
                              void* d_out, int out_size, void* d_ws, size_t ws_size,
                              hipStream_t stream) {
    const float* x    = (const float*)d_in[0];
    const float* k0   = (const float*)d_in[1];
    const float* k1   = (const float*)d_in[2];
    const float* k2   = (const float*)d_in[3];
    const float* k3   = (const float*)d_in[4];
    const float* bias = (const float*)d_in[5];
    float* out = (float*)d_out;
    unsigned short* wbuf = (unsigned short*)d_ws;  // 9216 bf16 = 18 KB

    recon_w<<<36, 256, 0, stream>>>(k0, k1, k2, k3, wbuf);
    // 8 images * (512/TH=64) * (512/TW=8) = 4096 blocks
    conv_mfma<<<4096, 256, 0, stream>>>(x, wbuf, bias, out);
}